// Round 2
// baseline (440.860 us; speedup 1.0000x reference)
//
#include <hip/hip_runtime.h>
#include <climits>

// ---------------------------------------------------------------------------
// GCN 2-layer + graclus pooling. Only 256x64 outputs are read, which depend
// on 512 "selected" nodes; conv work is restricted to the ~8.7k-node frontier
// (selected + their in-neighbors). Full-E work is reduced to:
//   Pass A: deg atomics (+ frontier-src marking)    [atomic-wb bound]
//   Pass B: dst-filtered edge compaction (~150k edges)
// Then a tiny CSR over the frontier feeds the aggregations; projection W is
// applied AFTER aggregation (linearity), so GEMMs are ~8.7k rows only.
// ---------------------------------------------------------------------------

#define NF_CAP 40960   // frontier cap: 512 sel * (1 + max indeg ~45) << this

__global__ void k_init(float* deg, unsigned char* mark1, unsigned char* mark2,
                       int* fidx, int* counts2, int* first, int* cnt,
                       int n, int nb) {
  int i = blockIdx.x * blockDim.x + threadIdx.x;
  if (i < n) { deg[i] = 1.0f; mark1[i] = 0; mark2[i] = 0; fidx[i] = -1; }
  if (i < NF_CAP) counts2[i] = 0;
  if (i < nb) first[i] = INT_MAX;
  if (i < 4) cnt[i] = 0;
}

// --- pooling selection (depends only on batch) ------------------------------
__global__ void k_first(const int* __restrict__ batch, int* first, int nc) {
  int c = blockIdx.x * blockDim.x + threadIdx.x;
  if (c >= nc) return;
  int b0 = batch[2 * c], b1 = batch[2 * c + 1];
  atomicMin(&first[min(b0, b1)], c);
}

__global__ void k_sel(const int* __restrict__ first, int* sel,
                      unsigned char* mark1, unsigned char* mark2, int nb, int nc) {
  int t = blockIdx.x * blockDim.x + threadIdx.x;
  if (t >= 2 * nb) return;
  int f = first[t >> 1];
  f = min(f, nc - 1);            // clamp INT_MAX (empty segment) like JAX gather
  int node = 2 * f + (t & 1);
  sel[t] = node;
  mark1[node] = 1;               // selected set
  mark2[node] = 1;               // frontier includes selected
}

// --- Pass A: full-E deg accumulation + frontier-src marking -----------------
__global__ void k_edgeA(const int* __restrict__ src, const int* __restrict__ dst,
                        const float* __restrict__ w, const unsigned char* __restrict__ mark1,
                        float* deg, unsigned char* mark2, int e) {
  int i = blockIdx.x * blockDim.x + threadIdx.x;
  if (i >= e) return;
  int d = dst[i];
  atomicAdd(&deg[d], w[i]);
  if (mark1[d]) mark2[src[i]] = 1;
}

__global__ void k_dinv(const float* __restrict__ deg, float* dinv, int n) {
  int i = blockIdx.x * blockDim.x + threadIdx.x;
  if (i < n) { float d = deg[i]; dinv[i] = d > 0.f ? rsqrtf(d) : 0.f; }
}

__global__ void k_compact(const unsigned char* __restrict__ mark2, int* list,
                          int* fidx, int* cntF, int n) {
  int i = blockIdx.x * blockDim.x + threadIdx.x;
  if (i < n && mark2[i]) {
    int p = atomicAdd(cntF, 1);
    if (p < NF_CAP) { list[p] = i; fidx[i] = p; }
  }
}

// --- Pass B: compact edges whose dst is in the frontier ---------------------
__global__ void k_edgeB(const int* __restrict__ src, const int* __restrict__ dst,
                        const float* __restrict__ w, const int* __restrict__ fidx,
                        int* counts2, int* cntE,
                        int* e_src, int* e_f, float* e_w, int e) {
  __shared__ int lcnt, lbase;
  if (threadIdx.x == 0) lcnt = 0;
  __syncthreads();
  int i = blockIdx.x * blockDim.x + threadIdx.x;
  int f = -1, pos = 0, s = 0;
  float wv = 0.f;
  if (i < e) {
    f = fidx[dst[i]];
    if (f >= 0) {
      pos = atomicAdd(&lcnt, 1);
      s = src[i];
      wv = w[i];
      atomicAdd(&counts2[f], 1);
    }
  }
  __syncthreads();
  if (threadIdx.x == 0 && lcnt > 0) lbase = atomicAdd(cntE, lcnt);
  __syncthreads();
  if (f >= 0) {
    int p = lbase + pos;
    e_src[p] = s; e_f[p] = f; e_w[p] = wv;
  }
}

// --- tiny exclusive scan over frontier counts (single block) ----------------
__global__ __launch_bounds__(1024) void k_scanF(const int* __restrict__ counts2,
                                                const int* __restrict__ cntF,
                                                const int* __restrict__ cntE,
                                                int* frowptr, int* fcursor) {
  __shared__ int sd[1024];
  __shared__ int carry;
  int t = threadIdx.x;
  int nf = min(*cntF, NF_CAP);
  if (t == 0) carry = 0;
  __syncthreads();
  for (int base = 0; base < nf; base += 1024) {
    int i = base + t;
    int v = (i < nf) ? counts2[i] : 0;
    sd[t] = v; __syncthreads();
    for (int off = 1; off < 1024; off <<= 1) {
      int a = (t >= off) ? sd[t - off] : 0;
      __syncthreads();
      sd[t] += a;
      __syncthreads();
    }
    int c = carry;
    if (i < nf) { int r = c + sd[t] - v; frowptr[i] = r; fcursor[i] = r; }
    __syncthreads();
    if (t == 1023) carry = c + sd[t];
    __syncthreads();
  }
  if (t == 0) frowptr[nf] = *cntE;
}

__global__ void k_scatF(const int* __restrict__ e_src, const int* __restrict__ e_f,
                        const float* __restrict__ e_w, const int* __restrict__ cntE,
                        const float* __restrict__ dinv, const int* __restrict__ list,
                        int* fcursor, int* fcols, float* fvals) {
  int m = *cntE;
  int stride = gridDim.x * blockDim.x;
  for (int i = blockIdx.x * blockDim.x + threadIdx.x; i < m; i += stride) {
    int f = e_f[i], s = e_src[i];
    int p = atomicAdd(&fcursor[f], 1);
    fcols[p] = s;
    fvals[p] = dinv[s] * e_w[i] * dinv[list[f]];
  }
}

// --- 128-d aggregation of raw x at frontier nodes (wave per row, compact) ---
__global__ void k_aggx(const float* __restrict__ x, const int* __restrict__ list,
                       const int* __restrict__ cntF, const int* __restrict__ frowptr,
                       const int* __restrict__ fcols, const float* __restrict__ fvals,
                       const float* __restrict__ dinv, float* __restrict__ aggx) {
  int lane = threadIdx.x & 63;
  int wid = (blockIdx.x * blockDim.x + threadIdx.x) >> 6;
  int nw = (gridDim.x * blockDim.x) >> 6;
  int m = min(*cntF, NF_CAP);
  const float2* x2 = (const float2*)x;
  float2* a2 = (float2*)aggx;
  for (int li = wid; li < m; li += nw) {
    int i = list[li];
    float dv = dinv[i];
    float2 xi = x2[(size_t)i * 64 + lane];
    float2 acc;
    acc.x = dv * dv * xi.x;
    acc.y = dv * dv * xi.y;
    int beg = frowptr[li], end = frowptr[li + 1];
    for (int p = beg; p < end; ++p) {
      int c = fcols[p];
      float v = fvals[p];
      float2 xc = x2[(size_t)c * 64 + lane];
      acc.x += v * xc.x;
      acc.y += v * xc.y;
    }
    a2[(size_t)li * 64 + lane] = acc;
  }
}

// --- rowwise GEMM: out[r] = A[r] @ W + bias (compact rows) -------------------
template <int K>
__global__ void k_gemm_rows(const float* __restrict__ A, const float* __restrict__ W,
                            const float* __restrict__ bias, const int* __restrict__ cntp,
                            int ncap, float* __restrict__ out) {
  __shared__ float Wl[K * 64];
  int t = threadIdx.x;
  for (int p = t; p < K * 16; p += blockDim.x)
    ((float4*)Wl)[p] = ((const float4*)W)[p];
  __syncthreads();
  int lane = t & 63;
  int wid = (blockIdx.x * blockDim.x + t) >> 6;
  int nw = (gridDim.x * blockDim.x) >> 6;
  int m = cntp ? min(*cntp, ncap) : ncap;
  for (int r = wid; r < m; r += nw) {
    const float* a = A + (size_t)r * K;
    float acc = bias[lane];
#pragma unroll
    for (int k = 0; k < K; k += 4) {
      float4 av = *(const float4*)(a + k);   // wave-uniform broadcast
      acc += av.x * Wl[(k + 0) * 64 + lane] + av.y * Wl[(k + 1) * 64 + lane] +
             av.z * Wl[(k + 2) * 64 + lane] + av.w * Wl[(k + 3) * 64 + lane];
    }
    out[(size_t)r * 64 + lane] = acc;
  }
}

// --- 64-d aggregation of h1 at the 512 selected nodes ------------------------
__global__ void k_aggh(const float* __restrict__ h1, const int* __restrict__ sel,
                       const int* __restrict__ fidx, const int* __restrict__ frowptr,
                       const int* __restrict__ fcols, const float* __restrict__ fvals,
                       const float* __restrict__ dinv, float* __restrict__ aggh, int nsel) {
  int lane = threadIdx.x & 63;
  int wid = (blockIdx.x * blockDim.x + threadIdx.x) >> 6;
  if (wid >= nsel) return;
  int i = sel[wid];
  int f = fidx[i];
  if (f < 0) return;
  float dv = dinv[i];
  float acc = dv * dv * h1[(size_t)f * 64 + lane];
  int beg = frowptr[f], end = frowptr[f + 1];
  for (int p = beg; p < end; ++p) {
    int g = fidx[fcols[p]];            // neighbor of sel => in frontier
    acc += fvals[p] * h1[(size_t)g * 64 + lane];
  }
  aggh[(size_t)wid * 64 + lane] = acc;
}

__global__ void k_out(const float* __restrict__ h2, float* __restrict__ out, int nb) {
  int j = threadIdx.x;
  int b = blockIdx.x;
  if (b >= nb) return;
  out[(size_t)b * 64 + j] =
      fmaxf(h2[(size_t)(2 * b) * 64 + j], h2[(size_t)(2 * b + 1) * 64 + j]);
}

extern "C" void kernel_launch(void* const* d_in, const int* in_sizes, int n_in,
                              void* d_out, int out_size, void* d_ws, size_t ws_size,
                              hipStream_t stream) {
  const float* x     = (const float*)d_in[0];
  const int*   ei    = (const int*)d_in[1];
  const float* ew    = (const float*)d_in[2];
  const int*   batch = (const int*)d_in[3];
  const float* W1    = (const float*)d_in[4];
  const float* b1    = (const float*)d_in[5];
  const float* W2    = (const float*)d_in[6];
  const float* b2    = (const float*)d_in[7];

  const int E  = in_sizes[2];
  const int N  = in_sizes[3];
  const int B  = out_size / 64;
  const int NC = N / 2;
  const int* srcI = ei;
  const int* dstI = ei + E;

  char* p = (char*)d_ws;
  auto alloc = [&](size_t bytes) -> char* {
    char* r = p;
    p += (bytes + 255) & ~size_t(255);
    return r;
  };
  float* deg     = (float*)alloc((size_t)N * 4);
  float* dinv    = (float*)alloc((size_t)N * 4);
  unsigned char* mark1 = (unsigned char*)alloc(N);
  unsigned char* mark2 = (unsigned char*)alloc(N);
  int*   fidx    = (int*)alloc((size_t)N * 4);
  int*   list    = (int*)alloc((size_t)NF_CAP * 4);
  int*   counts2 = (int*)alloc((size_t)NF_CAP * 4);
  int*   frowptr = (int*)alloc((size_t)(NF_CAP + 1) * 4);
  int*   fcursor = (int*)alloc((size_t)NF_CAP * 4);
  int*   first   = (int*)alloc((size_t)B * 4);
  int*   sel     = (int*)alloc((size_t)2 * B * 4);
  int*   cnt     = (int*)alloc(256);            // [0]=cntF, [1]=cntE
  int*   e_src   = (int*)alloc((size_t)E * 4);
  int*   e_f     = (int*)alloc((size_t)E * 4);
  float* e_w     = (float*)alloc((size_t)E * 4);
  int*   fcols   = (int*)alloc((size_t)E * 4);
  float* fvals   = (float*)alloc((size_t)E * 4);
  float* aggx    = (float*)alloc((size_t)NF_CAP * 128 * 4);
  float* h1      = (float*)alloc((size_t)NF_CAP * 64 * 4);
  float* aggh    = (float*)alloc((size_t)2 * B * 64 * 4);
  float* h2      = (float*)alloc((size_t)2 * B * 64 * 4);

  int gN = (N + 255) / 256;
  int gE = (E + 255) / 256;
  int* cntF = cnt;
  int* cntE = cnt + 1;

  k_init<<<gN, 256, 0, stream>>>(deg, mark1, mark2, fidx, counts2, first, cnt, N, B);
  k_first<<<(NC + 255) / 256, 256, 0, stream>>>(batch, first, NC);
  k_sel<<<(2 * B + 255) / 256, 256, 0, stream>>>(first, sel, mark1, mark2, B, NC);
  k_edgeA<<<gE, 256, 0, stream>>>(srcI, dstI, ew, mark1, deg, mark2, E);
  k_dinv<<<gN, 256, 0, stream>>>(deg, dinv, N);
  k_compact<<<gN, 256, 0, stream>>>(mark2, list, fidx, cntF, N);
  k_edgeB<<<gE, 256, 0, stream>>>(srcI, dstI, ew, fidx, counts2, cntE, e_src, e_f, e_w, E);
  k_scanF<<<1, 1024, 0, stream>>>(counts2, cntF, cntE, frowptr, fcursor);
  k_scatF<<<256, 256, 0, stream>>>(e_src, e_f, e_w, cntE, dinv, list, fcursor, fcols, fvals);
  k_aggx<<<2048, 256, 0, stream>>>(x, list, cntF, frowptr, fcols, fvals, dinv, aggx);
  k_gemm_rows<128><<<512, 256, 0, stream>>>(aggx, W1, b1, cntF, NF_CAP, h1);
  k_aggh<<<(2 * B + 3) / 4, 256, 0, stream>>>(h1, sel, fidx, frowptr, fcols, fvals, dinv, aggh, 2 * B);
  k_gemm_rows<64><<<(2 * B + 3) / 4, 256, 0, stream>>>(aggh, W2, b2, nullptr, 2 * B, h2);
  k_out<<<B, 64, 0, stream>>>(h2, (float*)d_out, B);
}

// Round 3
// 342.885 us; speedup vs baseline: 1.2857x; 1.2857x over previous
//
#include <hip/hip_runtime.h>
#include <climits>

// ---------------------------------------------------------------------------
// GCN 2-layer + graclus pooling. Only 256x64 outputs are read -> restrict conv
// to the ~8.7k-node frontier (512 selected + in-neighbors).
//   k_edgeA : full-E deg atomics into per-XCD partials + frontier marking
//   k_edgeB : dst-filtered edge compaction (~150k edges)
//   k_h1    : fused [aggregate x over frontier CSR] + [@W1 + b1]   (no aggx)
//   k_h2out : fused [aggregate h1 at 512 sel] + [@W2 + b2] + pairwise max
// Linearity: segment_sum(norm * (x@W)[src]) == segment_sum(norm * x[src]) @ W
// ---------------------------------------------------------------------------

#define NF_CAP 40960
#define NXCC 8

__device__ __forceinline__ int xcc8() {
  int v;
  asm volatile("s_getreg_b32 %0, hwreg(HW_REG_XCC_ID)" : "=s"(v));
  return v & (NXCC - 1);
}

__global__ void k_init(float* degp, unsigned char* mark1, unsigned char* mark2,
                       int* fidx, int* counts2, int* first, int* cnt,
                       int n, int nb) {
  int i = blockIdx.x * blockDim.x + threadIdx.x;
  if (i < n) {
#pragma unroll
    for (int c = 0; c < NXCC; ++c) degp[(size_t)c * n + i] = 0.f;
    mark1[i] = 0; mark2[i] = 0; fidx[i] = -1;
  }
  if (i < NF_CAP) counts2[i] = 0;
  if (i < nb) first[i] = INT_MAX;
  if (i < 4) cnt[i] = 0;
}

__global__ void k_first(const int* __restrict__ batch, int* first, int nc) {
  int c = blockIdx.x * blockDim.x + threadIdx.x;
  if (c >= nc) return;
  int b0 = batch[2 * c], b1 = batch[2 * c + 1];
  atomicMin(&first[min(b0, b1)], c);
}

__global__ void k_sel(const int* __restrict__ first, int* sel,
                      unsigned char* mark1, unsigned char* mark2, int nb, int nc) {
  int t = blockIdx.x * blockDim.x + threadIdx.x;
  if (t >= 2 * nb) return;
  int f = first[t >> 1];
  f = min(f, nc - 1);            // JAX gather clamps (empty-graph case)
  int node = 2 * f + (t & 1);
  sel[t] = node;
  mark1[node] = 1;
  mark2[node] = 1;
}

// --- Pass A: deg into per-XCD partial (L2-local lines) + frontier marking ---
__global__ void k_edgeA(const int* __restrict__ src, const int* __restrict__ dst,
                        const float* __restrict__ w, const unsigned char* __restrict__ mark1,
                        float* degp, unsigned char* mark2, int e, int n) {
  int i = blockIdx.x * blockDim.x + threadIdx.x;
  if (i >= e) return;
  int d = dst[i];
  float wv = w[i];
  float* dp = degp + (size_t)xcc8() * n;
  atomicAdd(&dp[d], wv);
  if (mark1[d]) mark2[src[i]] = 1;
}

__global__ void k_degsum(const float* __restrict__ degp, float* dinv, int n) {
  int i = blockIdx.x * blockDim.x + threadIdx.x;
  if (i >= n) return;
  float s = 1.f;                         // self-loop weight
#pragma unroll
  for (int c = 0; c < NXCC; ++c) s += degp[(size_t)c * n + i];
  dinv[i] = rsqrtf(s);
}

__global__ void k_compact(const unsigned char* __restrict__ mark2, int* list,
                          int* fidx, int* cntF, int n) {
  int i = blockIdx.x * blockDim.x + threadIdx.x;
  if (i < n && mark2[i]) {
    int p = atomicAdd(cntF, 1);
    if (p < NF_CAP) { list[p] = i; fidx[i] = p; }
  }
}

// --- Pass B: compact edges whose dst is in the frontier ---------------------
__global__ void k_edgeB(const int* __restrict__ src, const int* __restrict__ dst,
                        const float* __restrict__ w, const unsigned char* __restrict__ mark2,
                        const int* __restrict__ fidx, int* counts2, int* cntE,
                        int* e_src, int* e_f, float* e_w, int e) {
  __shared__ int lcnt, lbase;
  if (threadIdx.x == 0) lcnt = 0;
  __syncthreads();
  int i = blockIdx.x * blockDim.x + threadIdx.x;
  int f = -1, pos = 0, s = 0;
  float wv = 0.f;
  if (i < e) {
    int d = dst[i];
    if (mark2[d]) {
      f = fidx[d];
      if (f >= 0) {
        pos = atomicAdd(&lcnt, 1);
        s = src[i];
        wv = w[i];
        atomicAdd(&counts2[f], 1);
      }
    }
  }
  __syncthreads();
  if (threadIdx.x == 0 && lcnt > 0) lbase = atomicAdd(cntE, lcnt);
  __syncthreads();
  if (f >= 0) {
    int p = lbase + pos;
    e_src[p] = s; e_f[p] = f; e_w[p] = wv;
  }
}

// --- exclusive scan over frontier counts (single block) ---------------------
__global__ __launch_bounds__(1024) void k_scanF(const int* __restrict__ counts2,
                                                const int* __restrict__ cntF,
                                                const int* __restrict__ cntE,
                                                int* frowptr, int* fcursor) {
  __shared__ int sd[1024];
  __shared__ int carry;
  int t = threadIdx.x;
  int nf = min(*cntF, NF_CAP);
  if (t == 0) carry = 0;
  __syncthreads();
  for (int base = 0; base < nf; base += 1024) {
    int i = base + t;
    int v = (i < nf) ? counts2[i] : 0;
    sd[t] = v; __syncthreads();
    for (int off = 1; off < 1024; off <<= 1) {
      int a = (t >= off) ? sd[t - off] : 0;
      __syncthreads();
      sd[t] += a;
      __syncthreads();
    }
    int c = carry;
    if (i < nf) { int r = c + sd[t] - v; frowptr[i] = r; fcursor[i] = r; }
    __syncthreads();
    if (t == 1023) carry = c + sd[t];
    __syncthreads();
  }
  if (t == 0) frowptr[nf] = *cntE;
}

__global__ void k_scatF(const int* __restrict__ e_src, const int* __restrict__ e_f,
                        const float* __restrict__ e_w, const int* __restrict__ cntE,
                        const float* __restrict__ dinv,
                        int* fcursor, int* fcols, float* fvals) {
  int m = *cntE;
  int stride = gridDim.x * blockDim.x;
  for (int i = blockIdx.x * blockDim.x + threadIdx.x; i < m; i += stride) {
    int f = e_f[i], s = e_src[i];
    int p = atomicAdd(&fcursor[f], 1);
    fcols[p] = s;
    fvals[p] = dinv[s] * e_w[i];       // dst-side dinv factored into k_h1
  }
}

// --- fused: aggregate x over frontier CSR, then @W1 + b1 --------------------
__global__ __launch_bounds__(256) void k_h1(const float* __restrict__ x,
    const int* __restrict__ list, const int* __restrict__ cntF,
    const int* __restrict__ frowptr, const int* __restrict__ fcols,
    const float* __restrict__ fvals, const float* __restrict__ dinv,
    const float* __restrict__ W1, const float* __restrict__ b1,
    float* __restrict__ h1) {
  __shared__ float Wl[128 * 64];       // 32 KB
  __shared__ float sag[4][130];        // per-wave 128-d aggregate (padded)
  int t = threadIdx.x;
  for (int p = t; p < 128 * 16; p += 256)
    ((float4*)Wl)[p] = ((const float4*)W1)[p];
  __syncthreads();
  int lane = t & 63, wv = t >> 6;
  int wid = blockIdx.x * 4 + wv;
  int nw = gridDim.x * 4;
  int m = min(*cntF, NF_CAP);
  const float2* x2 = (const float2*)x;
  float bias = b1[lane];
  for (int li = wid; li < m; li += nw) {
    int i = list[li];
    float dv = dinv[i];
    float2 xi = x2[(size_t)i * 64 + lane];
    float2 acc = {0.f, 0.f};
    int beg = frowptr[li], end = frowptr[li + 1];
    for (int p = beg; p < end; ++p) {
      int c = fcols[p];
      float v = fvals[p];              // dinv[c]*w
      float2 xc = x2[(size_t)c * 64 + lane];
      acc.x += v * xc.x;
      acc.y += v * xc.y;
    }
    acc.x = dv * (acc.x + dv * xi.x);  // dv*(sum + dv*x_i)
    acc.y = dv * (acc.y + dv * xi.y);
    sag[wv][2 * lane] = acc.x;
    sag[wv][2 * lane + 1] = acc.y;
    asm volatile("s_waitcnt lgkmcnt(0)" ::: "memory");   // wave-local stage
    float o = bias;
#pragma unroll 8
    for (int k = 0; k < 128; ++k)
      o += sag[wv][k] * Wl[k * 64 + lane];
    h1[(size_t)li * 64 + lane] = o;
  }
}

// --- fused: aggregate h1 at 512 sel nodes, @W2 + b2, pairwise max, out ------
__global__ __launch_bounds__(128) void k_h2out(const float* __restrict__ h1,
    const int* __restrict__ sel, const int* __restrict__ fidx,
    const int* __restrict__ frowptr, const int* __restrict__ fcols,
    const float* __restrict__ fvals, const float* __restrict__ dinv,
    const float* __restrict__ W2, const float* __restrict__ b2,
    float* __restrict__ out, int nb) {
  __shared__ float Wl[64 * 64];        // 16 KB
  __shared__ float sag[2][64];
  __shared__ float hh[2][64];
  int t = threadIdx.x;
  for (int p = t; p < 64 * 16; p += 128)
    ((float4*)Wl)[p] = ((const float4*)W2)[p];
  __syncthreads();
  int lane = t & 63, wv = t >> 6;
  int b = blockIdx.x;
  if (b >= nb) return;
  int node = sel[2 * b + wv];
  int f = fidx[node];
  float dv = dinv[node];
  float acc = 0.f;
  int beg = frowptr[f], end = frowptr[f + 1];
  for (int p = beg; p < end; ++p) {
    int g = fidx[fcols[p]];            // neighbor of sel => in frontier
    acc += fvals[p] * h1[(size_t)g * 64 + lane];
  }
  acc = dv * (acc + dv * h1[(size_t)f * 64 + lane]);
  sag[wv][lane] = acc;
  __syncthreads();
  float o = b2[lane];
#pragma unroll 8
  for (int k = 0; k < 64; ++k)
    o += sag[wv][k] * Wl[k * 64 + lane];
  hh[wv][lane] = o;
  __syncthreads();
  if (wv == 0)
    out[(size_t)b * 64 + lane] = fmaxf(hh[0][lane], hh[1][lane]);
}

extern "C" void kernel_launch(void* const* d_in, const int* in_sizes, int n_in,
                              void* d_out, int out_size, void* d_ws, size_t ws_size,
                              hipStream_t stream) {
  const float* x     = (const float*)d_in[0];
  const int*   ei    = (const int*)d_in[1];
  const float* ew    = (const float*)d_in[2];
  const int*   batch = (const int*)d_in[3];
  const float* W1    = (const float*)d_in[4];
  const float* b1    = (const float*)d_in[5];
  const float* W2    = (const float*)d_in[6];
  const float* b2    = (const float*)d_in[7];

  const int E  = in_sizes[2];
  const int N  = in_sizes[3];
  const int B  = out_size / 64;
  const int NC = N / 2;
  const int* srcI = ei;
  const int* dstI = ei + E;

  char* p = (char*)d_ws;
  auto alloc = [&](size_t bytes) -> char* {
    char* r = p;
    p += (bytes + 255) & ~size_t(255);
    return r;
  };
  float* degp    = (float*)alloc((size_t)NXCC * N * 4);
  float* dinv    = (float*)alloc((size_t)N * 4);
  unsigned char* mark1 = (unsigned char*)alloc(N);
  unsigned char* mark2 = (unsigned char*)alloc(N);
  int*   fidx    = (int*)alloc((size_t)N * 4);
  int*   list    = (int*)alloc((size_t)NF_CAP * 4);
  int*   counts2 = (int*)alloc((size_t)NF_CAP * 4);
  int*   frowptr = (int*)alloc((size_t)(NF_CAP + 1) * 4);
  int*   fcursor = (int*)alloc((size_t)NF_CAP * 4);
  int*   first   = (int*)alloc((size_t)B * 4);
  int*   sel     = (int*)alloc((size_t)2 * B * 4);
  int*   cnt     = (int*)alloc(256);           // [0]=cntF, [1]=cntE
  int*   e_src   = (int*)alloc((size_t)E * 4);
  int*   e_f     = (int*)alloc((size_t)E * 4);
  float* e_w     = (float*)alloc((size_t)E * 4);
  int*   fcols   = (int*)alloc((size_t)E * 4);
  float* fvals   = (float*)alloc((size_t)E * 4);
  float* h1      = (float*)alloc((size_t)NF_CAP * 64 * 4);

  int gN = (N + 255) / 256;
  int gE = (E + 255) / 256;
  int* cntF = cnt;
  int* cntE = cnt + 1;

  k_init<<<gN, 256, 0, stream>>>(degp, mark1, mark2, fidx, counts2, first, cnt, N, B);
  k_first<<<(NC + 255) / 256, 256, 0, stream>>>(batch, first, NC);
  k_sel<<<(2 * B + 255) / 256, 256, 0, stream>>>(first, sel, mark1, mark2, B, NC);
  k_edgeA<<<gE, 256, 0, stream>>>(srcI, dstI, ew, mark1, degp, mark2, E, N);
  k_degsum<<<gN, 256, 0, stream>>>(degp, dinv, N);
  k_compact<<<gN, 256, 0, stream>>>(mark2, list, fidx, cntF, N);
  k_edgeB<<<gE, 256, 0, stream>>>(srcI, dstI, ew, mark2, fidx, counts2, cntE, e_src, e_f, e_w, E);
  k_scanF<<<1, 1024, 0, stream>>>(counts2, cntF, cntE, frowptr, fcursor);
  k_scatF<<<256, 256, 0, stream>>>(e_src, e_f, e_w, cntE, dinv, fcursor, fcols, fvals);
  k_h1<<<1024, 256, 0, stream>>>(x, list, cntF, frowptr, fcols, fvals, dinv, W1, b1, h1);
  k_h2out<<<B, 128, 0, stream>>>(h1, sel, fidx, frowptr, fcols, fvals, dinv, W2, b2,
                                 (float*)d_out, B);
}

// Round 4
// 307.760 us; speedup vs baseline: 1.4325x; 1.1141x over previous
//
#include <hip/hip_runtime.h>
#include <climits>

// ---------------------------------------------------------------------------
// GCN 2-layer + graclus pooling, frontier-restricted (~8.7k nodes).
// Degree build is now atomic-free: LDS-bucketed two-pass histogram.
//   k_bkt    : chunk edges -> LDS sort by 1024-node bucket -> bucket-contig dump
//   k_degred : per-bucket LDS accumulate -> dinv (no device atomics)
//   k_edgeB  : dst-filtered edge compaction (~150k edges into frontier)
//   k_h1     : fused [aggregate x over frontier CSR] + [@W1 + b1]
//   k_h2out  : fused [aggregate h1 at 512 sel] + [@W2 + b2] + pairwise max
// ---------------------------------------------------------------------------

#define NF_CAP 40960
#define CHUNK 4096

__global__ void k_init(unsigned char* mark1, unsigned char* mark2,
                       int* fidx, int* counts2, int* first, int* cnt,
                       int* gcur, int n, int nb) {
  int i = blockIdx.x * blockDim.x + threadIdx.x;
  if (i < n) { mark1[i] = 0; mark2[i] = 0; fidx[i] = -1; }
  if (i < NF_CAP) counts2[i] = 0;
  if (i < nb) first[i] = INT_MAX;
  if (i < 4) cnt[i] = 0;
  if (i < 128) gcur[i] = 0;
}

__global__ void k_first(const int* __restrict__ batch, int* first, int nc) {
  int c = blockIdx.x * blockDim.x + threadIdx.x;
  if (c >= nc) return;
  int b0 = batch[2 * c], b1 = batch[2 * c + 1];
  atomicMin(&first[min(b0, b1)], c);
}

__global__ void k_sel(const int* __restrict__ first, int* sel,
                      unsigned char* mark1, unsigned char* mark2, int nb, int nc) {
  int t = blockIdx.x * blockDim.x + threadIdx.x;
  if (t >= 2 * nb) return;
  int f = first[t >> 1];
  f = min(f, nc - 1);            // JAX gather clamps (empty-graph case)
  int node = 2 * f + (t & 1);
  sel[t] = node;
  mark1[node] = 1;
  mark2[node] = 1;
}

// --- pass 1: bucket edges by dst>>10, LDS-sorted, bucket-contiguous dump ----
__global__ __launch_bounds__(256) void k_bkt(const int* __restrict__ src,
    const int* __restrict__ dst, const float* __restrict__ w,
    const unsigned char* __restrict__ mark1, unsigned char* mark2,
    int* gcur, uint2* bktbuf, int cap, int e) {
  __shared__ int scnt[128], sbase[128], sgb[128];
  __shared__ unsigned int sd[CHUNK];
  __shared__ float sw[CHUNK];
  int t = threadIdx.x;
  if (t < 128) scnt[t] = 0;
  __syncthreads();
  int i0 = blockIdx.x * CHUNK;
  int rd[16];
  float rw[16];
#pragma unroll
  for (int k = 0; k < 16; ++k) {
    int i = i0 + t + k * 256;
    if (i < e) {
      int d = dst[i];
      rd[k] = d;
      rw[k] = w[i];
      atomicAdd(&scnt[d >> 10], 1);
      if (mark1[d]) mark2[src[i]] = 1;    // frontier-src marking (rare)
    } else {
      rd[k] = -1;
    }
  }
  __syncthreads();
  // exclusive scan of scnt[0..127] (Hillis-Steele, uniform barriers)
  if (t < 128) sbase[t] = scnt[t];
  __syncthreads();
  for (int off = 1; off < 128; off <<= 1) {
    int a = (t < 128 && t >= off) ? sbase[t - off] : 0;
    __syncthreads();
    if (t < 128) sbase[t] += a;
    __syncthreads();
  }
  if (t < 128) {
    int c = scnt[t];
    sbase[t] -= c;                              // inclusive -> exclusive
    sgb[t] = c ? atomicAdd(&gcur[t], c) : 0;    // ~98 device atomics / block
  }
  __syncthreads();
  if (t < 128) scnt[t] = 0;
  __syncthreads();
#pragma unroll
  for (int k = 0; k < 16; ++k) {
    if (rd[k] >= 0) {
      int b = rd[k] >> 10;
      int pos = atomicAdd(&scnt[b], 1) + sbase[b];
      sd[pos] = (unsigned int)rd[k];
      sw[pos] = rw[k];
    }
  }
  __syncthreads();
  int tot = min(CHUNK, e - i0);
  for (int j = t; j < tot; j += 256) {
    unsigned int d = sd[j];
    int b = d >> 10;
    int gi = b * cap + sgb[b] + (j - sbase[b]);
    bktbuf[gi] = make_uint2(d & 1023u, __float_as_uint(sw[j]));
  }
}

// --- pass 2: per-bucket LDS reduce -> dinv (fuses degsum) --------------------
__global__ __launch_bounds__(1024) void k_degred(const int* __restrict__ gcur,
    const uint2* __restrict__ bktbuf, int cap, float* dinv, int n) {
  __shared__ float acc[1024];
  int t = threadIdx.x, b = blockIdx.x;
  acc[t] = 0.f;
  __syncthreads();
  int m = min(gcur[b], cap);
  const uint2* base = bktbuf + (size_t)b * cap;
  for (int j = t; j < m; j += 1024) {
    uint2 u = base[j];
    atomicAdd(&acc[u.x], __uint_as_float(u.y));   // LDS fp32 atomic
  }
  __syncthreads();
  int i = (b << 10) + t;
  if (i < n) dinv[i] = rsqrtf(1.0f + acc[t]);     // +1 = self-loop weight
}

__global__ void k_compact(const unsigned char* __restrict__ mark2, int* list,
                          int* fidx, int* cntF, int n) {
  int i = blockIdx.x * blockDim.x + threadIdx.x;
  if (i < n && mark2[i]) {
    int p = atomicAdd(cntF, 1);
    if (p < NF_CAP) { list[p] = i; fidx[i] = p; }
  }
}

// --- compact edges whose dst is in the frontier ------------------------------
__global__ void k_edgeB(const int* __restrict__ src, const int* __restrict__ dst,
                        const float* __restrict__ w, const unsigned char* __restrict__ mark2,
                        const int* __restrict__ fidx, int* counts2, int* cntE,
                        int* e_src, int* e_f, float* e_w, int e) {
  __shared__ int lcnt, lbase;
  if (threadIdx.x == 0) lcnt = 0;
  __syncthreads();
  int i = blockIdx.x * blockDim.x + threadIdx.x;
  int f = -1, pos = 0, s = 0;
  float wv = 0.f;
  if (i < e) {
    int d = dst[i];
    if (mark2[d]) {
      f = fidx[d];
      if (f >= 0) {
        pos = atomicAdd(&lcnt, 1);
        s = src[i];
        wv = w[i];
        atomicAdd(&counts2[f], 1);
      }
    }
  }
  __syncthreads();
  if (threadIdx.x == 0 && lcnt > 0) lbase = atomicAdd(cntE, lcnt);
  __syncthreads();
  if (f >= 0) {
    int p = lbase + pos;
    e_src[p] = s; e_f[p] = f; e_w[p] = wv;
  }
}

__global__ __launch_bounds__(1024) void k_scanF(const int* __restrict__ counts2,
                                                const int* __restrict__ cntF,
                                                const int* __restrict__ cntE,
                                                int* frowptr, int* fcursor) {
  __shared__ int sd[1024];
  __shared__ int carry;
  int t = threadIdx.x;
  int nf = min(*cntF, NF_CAP);
  if (t == 0) carry = 0;
  __syncthreads();
  for (int base = 0; base < nf; base += 1024) {
    int i = base + t;
    int v = (i < nf) ? counts2[i] : 0;
    sd[t] = v; __syncthreads();
    for (int off = 1; off < 1024; off <<= 1) {
      int a = (t >= off) ? sd[t - off] : 0;
      __syncthreads();
      sd[t] += a;
      __syncthreads();
    }
    int c = carry;
    if (i < nf) { int r = c + sd[t] - v; frowptr[i] = r; fcursor[i] = r; }
    __syncthreads();
    if (t == 1023) carry = c + sd[t];
    __syncthreads();
  }
  if (t == 0) frowptr[nf] = *cntE;
}

__global__ void k_scatF(const int* __restrict__ e_src, const int* __restrict__ e_f,
                        const float* __restrict__ e_w, const int* __restrict__ cntE,
                        const float* __restrict__ dinv,
                        int* fcursor, int* fcols, float* fvals) {
  int m = *cntE;
  int stride = gridDim.x * blockDim.x;
  for (int i = blockIdx.x * blockDim.x + threadIdx.x; i < m; i += stride) {
    int f = e_f[i], s = e_src[i];
    int p = atomicAdd(&fcursor[f], 1);
    fcols[p] = s;
    fvals[p] = dinv[s] * e_w[i];       // dst-side dinv applied in k_h1
  }
}

// --- fused: aggregate x over frontier CSR, then @W1 + b1 ---------------------
__global__ __launch_bounds__(256) void k_h1(const float* __restrict__ x,
    const int* __restrict__ list, const int* __restrict__ cntF,
    const int* __restrict__ frowptr, const int* __restrict__ fcols,
    const float* __restrict__ fvals, const float* __restrict__ dinv,
    const float* __restrict__ W1, const float* __restrict__ b1,
    float* __restrict__ h1) {
  __shared__ float Wl[128 * 64];       // 32 KB
  __shared__ float sag[4][130];
  int t = threadIdx.x;
  for (int p = t; p < 128 * 16; p += 256)
    ((float4*)Wl)[p] = ((const float4*)W1)[p];
  __syncthreads();
  int lane = t & 63, wv = t >> 6;
  int wid = blockIdx.x * 4 + wv;
  int nw = gridDim.x * 4;
  int m = min(*cntF, NF_CAP);
  const float2* x2 = (const float2*)x;
  float bias = b1[lane];
  for (int li = wid; li < m; li += nw) {
    int i = list[li];
    float dv = dinv[i];
    float2 xi = x2[(size_t)i * 64 + lane];
    float2 acc = {0.f, 0.f};
    int beg = frowptr[li], end = frowptr[li + 1];
    for (int p = beg; p < end; ++p) {
      int c = fcols[p];
      float v = fvals[p];
      float2 xc = x2[(size_t)c * 64 + lane];
      acc.x += v * xc.x;
      acc.y += v * xc.y;
    }
    acc.x = dv * (acc.x + dv * xi.x);
    acc.y = dv * (acc.y + dv * xi.y);
    sag[wv][2 * lane] = acc.x;
    sag[wv][2 * lane + 1] = acc.y;
    asm volatile("s_waitcnt lgkmcnt(0)" ::: "memory");
    float o = bias;
#pragma unroll 8
    for (int k = 0; k < 128; ++k)
      o += sag[wv][k] * Wl[k * 64 + lane];
    h1[(size_t)li * 64 + lane] = o;
  }
}

// --- fused: aggregate h1 at 512 sel nodes, @W2 + b2, pairwise max, out -------
__global__ __launch_bounds__(128) void k_h2out(const float* __restrict__ h1,
    const int* __restrict__ sel, const int* __restrict__ fidx,
    const int* __restrict__ frowptr, const int* __restrict__ fcols,
    const float* __restrict__ fvals, const float* __restrict__ dinv,
    const float* __restrict__ W2, const float* __restrict__ b2,
    float* __restrict__ out, int nb) {
  __shared__ float Wl[64 * 64];
  __shared__ float sag[2][64];
  __shared__ float hh[2][64];
  int t = threadIdx.x;
  for (int p = t; p < 64 * 16; p += 128)
    ((float4*)Wl)[p] = ((const float4*)W2)[p];
  __syncthreads();
  int lane = t & 63, wv = t >> 6;
  int b = blockIdx.x;
  if (b >= nb) return;
  int node = sel[2 * b + wv];
  int f = fidx[node];
  float dv = dinv[node];
  float acc = 0.f;
  int beg = frowptr[f], end = frowptr[f + 1];
  for (int p = beg; p < end; ++p) {
    int g = fidx[fcols[p]];
    acc += fvals[p] * h1[(size_t)g * 64 + lane];
  }
  acc = dv * (acc + dv * h1[(size_t)f * 64 + lane]);
  sag[wv][lane] = acc;
  __syncthreads();
  float o = b2[lane];
#pragma unroll 8
  for (int k = 0; k < 64; ++k)
    o += sag[wv][k] * Wl[k * 64 + lane];
  hh[wv][lane] = o;
  __syncthreads();
  if (wv == 0)
    out[(size_t)b * 64 + lane] = fmaxf(hh[0][lane], hh[1][lane]);
}

extern "C" void kernel_launch(void* const* d_in, const int* in_sizes, int n_in,
                              void* d_out, int out_size, void* d_ws, size_t ws_size,
                              hipStream_t stream) {
  const float* x     = (const float*)d_in[0];
  const int*   ei    = (const int*)d_in[1];
  const float* ew    = (const float*)d_in[2];
  const int*   batch = (const int*)d_in[3];
  const float* W1    = (const float*)d_in[4];
  const float* b1    = (const float*)d_in[5];
  const float* W2    = (const float*)d_in[6];
  const float* b2    = (const float*)d_in[7];

  const int E  = in_sizes[2];
  const int N  = in_sizes[3];
  const int B  = out_size / 64;
  const int NC = N / 2;
  const int* srcI = ei;
  const int* dstI = ei + E;

  const int NBKT = (N + 1023) >> 10;              // 98 for N=100k
  const int CAP  = ((E + NBKT - 1) / NBKT) * 2;   // ~2x expected bucket load

  char* p = (char*)d_ws;
  auto alloc = [&](size_t bytes) -> char* {
    char* r = p;
    p += (bytes + 255) & ~size_t(255);
    return r;
  };
  float* dinv    = (float*)alloc((size_t)N * 4);
  unsigned char* mark1 = (unsigned char*)alloc(N);
  unsigned char* mark2 = (unsigned char*)alloc(N);
  int*   fidx    = (int*)alloc((size_t)N * 4);
  int*   list    = (int*)alloc((size_t)NF_CAP * 4);
  int*   counts2 = (int*)alloc((size_t)NF_CAP * 4);
  int*   frowptr = (int*)alloc((size_t)(NF_CAP + 1) * 4);
  int*   fcursor = (int*)alloc((size_t)NF_CAP * 4);
  int*   first   = (int*)alloc((size_t)B * 4);
  int*   sel     = (int*)alloc((size_t)2 * B * 4);
  int*   cnt     = (int*)alloc(256);              // [0]=cntF, [1]=cntE
  int*   gcur    = (int*)alloc(128 * 4);
  uint2* bktbuf  = (uint2*)alloc((size_t)NBKT * CAP * 8);
  int*   e_src   = (int*)alloc((size_t)E * 4);
  int*   e_f     = (int*)alloc((size_t)E * 4);
  float* e_w     = (float*)alloc((size_t)E * 4);
  int*   fcols   = (int*)alloc((size_t)E * 4);
  float* fvals   = (float*)alloc((size_t)E * 4);
  float* h1      = (float*)alloc((size_t)NF_CAP * 64 * 4);

  int gN = (N + 255) / 256;
  int gE = (E + 255) / 256;
  int gB = (E + CHUNK - 1) / CHUNK;
  int* cntF = cnt;
  int* cntE = cnt + 1;

  k_init<<<gN, 256, 0, stream>>>(mark1, mark2, fidx, counts2, first, cnt, gcur, N, B);
  k_first<<<(NC + 255) / 256, 256, 0, stream>>>(batch, first, NC);
  k_sel<<<(2 * B + 255) / 256, 256, 0, stream>>>(first, sel, mark1, mark2, B, NC);
  k_bkt<<<gB, 256, 0, stream>>>(srcI, dstI, ew, mark1, mark2, gcur, bktbuf, CAP, E);
  k_degred<<<NBKT, 1024, 0, stream>>>(gcur, bktbuf, CAP, dinv, N);
  k_compact<<<gN, 256, 0, stream>>>(mark2, list, fidx, cntF, N);
  k_edgeB<<<gE, 256, 0, stream>>>(srcI, dstI, ew, mark2, fidx, counts2, cntE, e_src, e_f, e_w, E);
  k_scanF<<<1, 1024, 0, stream>>>(counts2, cntF, cntE, frowptr, fcursor);
  k_scatF<<<256, 256, 0, stream>>>(e_src, e_f, e_w, cntE, dinv, fcursor, fcols, fvals);
  k_h1<<<1024, 256, 0, stream>>>(x, list, cntF, frowptr, fcols, fvals, dinv, W1, b1, h1);
  k_h2out<<<B, 128, 0, stream>>>(h1, sel, fidx, frowptr, fcols, fvals, dinv, W2, b2,
                                 (float*)d_out, B);
}